// Round 11
// baseline (249.251 us; speedup 1.0000x reference)
//
#include <hip/hip_runtime.h>
#include <math.h>

// Problem constants (reference: B=4, N=8192, points are [B,N,3] fp32)
#define BATCH 4
#define NPTS 8192
#define BN (BATCH * NPTS)
#define NZB 16                 // 4 searches x 4 batches
#define QN (NZB * NPTS)        // 131072 total queries
#define TAU 1.0e-2f            // flag margin (R10-proven; analytic 2*eps ~3e-3)

// Workspace: [0] double acc | [8] uint ticket | [64] int idx_all[QN] (512KB)
//            [+512K] float part_d[SPL][QN] (SPL*512KB)
//            [after] ushort bpack[QN][16]  (4MB)

using frag_ab = __attribute__((ext_vector_type(8))) short;    // 8 bf16
using frag_c16 = __attribute__((ext_vector_type(16))) float;  // 16 fp32

__device__ __forceinline__ void pick_ab(int z, const float* pw, const float* pp,
                                        const float* tw, const float* tp,
                                        const float** qa, const float** cb) {
  if (z == 0)      { *qa = pw; *cb = pp; }
  else if (z == 1) { *qa = pp; *cb = pw; }
  else if (z == 2) { *qa = tw; *cb = tp; }
  else             { *qa = tp; *cb = tw; }
}

__device__ __forceinline__ unsigned short f2bf(float x) {   // RNE
  unsigned int u = __float_as_uint(x);
  u += 0x7fffu + ((u >> 16) & 1u);
  return (unsigned short)(u >> 16);
}
__device__ __forceinline__ float bf2f(unsigned short h) {
  return __uint_as_float(((unsigned int)h) << 16);
}

// ---------------------------------------------------------------------------
// Pass 0 (R10-proven): pack candidates, 16 bf16 K-slots (32B) each:
//  B[k] = [bhx,bhy,bhz, bhx,bhy,bhz, blx,bly,blz, blx,bly,blz, b2h,b2l, 0,0]
// Pairs with A = [-2ah(xyz), -2al(xyz), -2ah(xyz), -2al(xyz), 1,1, 0,0]
// => sum_k A*B = -2(ah+al).(bh+bl) + b2h+b2l  (all 4 cross terms).
// ---------------------------------------------------------------------------
__global__ __launch_bounds__(256) void pack_kernel(
    const float* __restrict__ pw, const float* __restrict__ pp,
    const float* __restrict__ tw, const float* __restrict__ tp,
    unsigned short* __restrict__ bpack) {
  const int g = blockIdx.x * 256 + threadIdx.x;   // [0, QN)
  const int zb = g >> 13;
  const int n = g & (NPTS - 1);
  const int z = zb >> 2;
  const int b = zb & 3;
  const float* qa;
  const float* cb;
  pick_ab(z, pw, pp, tw, tp, &qa, &cb);

  const float* c = cb + ((size_t)b * NPTS + n) * 3;
  const float bx = c[0], by = c[1], bz = c[2];
  unsigned short bh[3], bl[3];
  const float bf[3] = {bx, by, bz};
  #pragma unroll
  for (int d = 0; d < 3; ++d) {
    bh[d] = f2bf(bf[d]);
    bl[d] = f2bf(bf[d] - bf2f(bh[d]));
  }
  const float b2 = fmaf(bx, bx, fmaf(by, by, bz * bz));
  const unsigned short b2h = f2bf(b2);
  const unsigned short b2l = f2bf(b2 - bf2f(b2h));

  unsigned short v[16] = {bh[0], bh[1], bh[2], bh[0], bh[1], bh[2],
                          bl[0], bl[1], bl[2], bl[0], bl[1], bl[2],
                          b2h, b2l, 0, 0};
  uint4* dst = (uint4*)(bpack + (size_t)g * 16);
  const uint4* src = (const uint4*)v;
  dst[0] = src[0];
  dst[1] = src[1];
}

// ---------------------------------------------------------------------------
// Pass 1: 32x32x16 MFMA approx-min scan. K=16 fits all 14 bf16-split slots
// (no wasted K half, unlike R10's 16x16x32). Block 256 = 4 waves; each wave
// owns 64 queries (2 A-frags of 32) and sweeps the block's SLICE candidates.
// Layouts: A[m=lane&31][k=(lane>>5)*8+j]; B[k=(lane>>5)*8+j][n=lane&31]
// (same family as the R10-verified 16x16x32 mapping);
// C/D col=lane&31, row=(reg&3)+8*(reg>>2)+4*(lane>>5) [HW-verified m74/m101].
// Per ct: 1 ds_read_b128 + 2 MFMA + 32 fmin.  grid = (32, SPL, NZB).
// ---------------------------------------------------------------------------
template <int SPL>
__global__ __launch_bounds__(256, 4) void nn_mfma_scan(
    const float* __restrict__ pw, const float* __restrict__ pp,
    const float* __restrict__ tw, const float* __restrict__ tp,
    const unsigned short* __restrict__ bpack, float* __restrict__ part_d) {
  constexpr int SLICE = NPTS / SPL;
  constexpr int NCT = SLICE / 32;                 // candidate tiles of 32
  __shared__ __align__(16) unsigned short lds_b[SLICE * 16];  // SLICE*32B

  const int zb = blockIdx.z;
  const int z = zb >> 2;
  const int b = zb & 3;
  const float* qa;
  const float* cb;
  pick_ab(z, pw, pp, tw, tp, &qa, &cb);
  (void)cb;

  const int tid = threadIdx.x;

  // Stage packed B slice into LDS, xor-swizzled 16B granules.
  {
    const uint4* src =
        (const uint4*)(bpack + ((size_t)zb * NPTS + blockIdx.y * SLICE) * 16);
    uint4* dst = (uint4*)lds_b;
    for (int i = tid; i < SLICE * 2; i += 256) {
      const int pg = i ^ ((i >> 3) & 7);
      dst[pg] = src[i];
    }
  }
  __syncthreads();

  const int wv = tid >> 6;
  const int lane = tid & 63;
  const int col = lane & 31;        // m (query row) for A, n (candidate) for B
  const int half = lane >> 5;       // K half: k = half*8 + j
  const int qbase = blockIdx.x * 256 + wv * 64;

  // Build 2 A-frags (queries qbase + qt*32 + col).
  // Slot table S[16] = [-2ah xyz, -2al xyz, -2ah xyz, -2al xyz, 1,1, 0,0];
  // lane holds slots half*8 .. half*8+7.
  frag_ab A[2];
  #pragma unroll
  for (int qt = 0; qt < 2; ++qt) {
    const int n = qbase + qt * 32 + col;
    const float* q = qa + ((size_t)b * NPTS + n) * 3;
    unsigned short h[3], l[3];
    #pragma unroll
    for (int d = 0; d < 3; ++d) {
      const float a = q[d];
      const unsigned short ah = f2bf(a);
      const unsigned short al = f2bf(a - bf2f(ah));
      h[d] = f2bf(-2.0f * bf2f(ah));   // exact scale by -2
      l[d] = f2bf(-2.0f * bf2f(al));
    }
    const short ONE = (short)0x3F80;   // bf16 1.0
    unsigned short S[16] = {h[0], h[1], h[2], l[0], l[1], l[2],
                            h[0], h[1], h[2], l[0], l[1], l[2],
                            ONE, ONE, 0, 0};
    frag_ab fa;
    #pragma unroll
    for (int j = 0; j < 8; ++j) fa[j] = (short)S[half * 8 + j];
    A[qt] = fa;
  }

  float dmin[2][16];
  #pragma unroll
  for (int qt = 0; qt < 2; ++qt)
    #pragma unroll
    for (int r = 0; r < 16; ++r) dmin[qt][r] = INFINITY;

  const frag_ab* lb = (const frag_ab*)lds_b;
  const frag_c16 zc = {0.f, 0.f, 0.f, 0.f, 0.f, 0.f, 0.f, 0.f,
                       0.f, 0.f, 0.f, 0.f, 0.f, 0.f, 0.f, 0.f};

  for (int ct = 0; ct < NCT; ++ct) {
    const int g = ct * 64 + col * 2 + half;      // candidate ct*32+col, K-half
    const frag_ab Bf = lb[g ^ ((g >> 3) & 7)];   // ds_read_b128
    #pragma unroll
    for (int qt = 0; qt < 2; ++qt) {
      const frag_c16 D =
          __builtin_amdgcn_mfma_f32_32x32x16_bf16(A[qt], Bf, zc, 0, 0, 0);
      #pragma unroll
      for (int r = 0; r < 16; ++r) dmin[qt][r] = fminf(dmin[qt][r], D[r]);
    }
  }

  // Min over the 32 candidate-columns (lanes within same K-half: offsets 1..16
  // only touch lane bits 0..4, so each half reduces independently — rows held
  // by a lane depend only on 'half', which is preserved).
  #pragma unroll
  for (int off = 1; off < 32; off <<= 1)
    #pragma unroll
    for (int qt = 0; qt < 2; ++qt)
      #pragma unroll
      for (int r = 0; r < 16; ++r)
        dmin[qt][r] = fminf(dmin[qt][r], __shfl_xor(dmin[qt][r], off));

  if (col == 0) {   // lanes 0 and 32: 16 rows each, in 4 runs of 4 -> float4
    float* base = part_d + (size_t)blockIdx.y * QN + (size_t)zb * NPTS;
    #pragma unroll
    for (int qt = 0; qt < 2; ++qt)
      #pragma unroll
      for (int blk = 0; blk < 4; ++blk) {
        const int m0 = qbase + qt * 32 + blk * 8 + half * 4;  // row runs
        float4 v = make_float4(dmin[qt][blk * 4 + 0], dmin[qt][blk * 4 + 1],
                               dmin[qt][blk * 4 + 2], dmin[qt][blk * 4 + 3]);
        *(float4*)(base + m0) = v;
      }
  }
}

// ---------------------------------------------------------------------------
// Pass 2 (R10-proven): merge + flag + exact fp32 rescan. Flag every split
// with approx-min <= m_tilde + TAU (provably contains the true argmin and
// all exact ties); rescan flagged slices in exact fp32 with lexicographic
// (d, index) first-min == jnp.argmin. Zeroes acc+ticket.
// ---------------------------------------------------------------------------
template <int SPL>
__global__ __launch_bounds__(1024) void nn_merge_flag_rescan(
    const float* __restrict__ pw, const float* __restrict__ pp,
    const float* __restrict__ tw, const float* __restrict__ tp,
    const float* __restrict__ part_d, int* __restrict__ idx_all,
    double* __restrict__ acc, unsigned int* __restrict__ ticket) {
  constexpr int SLICE = NPTS / SPL;
  constexpr int NIT = SLICE / 64;
  __shared__ float sm[SPL][64];

  if (blockIdx.x == 0 && threadIdx.x == 0) { *acc = 0.0; *ticket = 0u; }

  const int tid = threadIdx.x;
  const int wv = tid >> 6;
  const int lane = tid & 63;
  const int qid0 = blockIdx.x * 64;

  for (int s = wv; s < SPL; s += 16)
    sm[s][lane] = part_d[(size_t)s * QN + qid0 + lane];
  __syncthreads();

  const int zb = qid0 >> 13;
  const int z = zb >> 2;
  const int b = zb & 3;
  const float* qa;
  const float* cb;
  pick_ab(z, pw, pp, tw, tp, &qa, &cb);
  const float* qb0 = qa + (size_t)b * NPTS * 3;
  const float* cbb = cb + (size_t)b * NPTS * 3;
  const int n0 = qid0 & (NPTS - 1);

  #pragma unroll
  for (int j = 0; j < 4; ++j) {
    const int lq = wv * 4 + j;
    const float* q = qb0 + (size_t)(n0 + lq) * 3;   // wave-uniform
    const float qx = -2.0f * q[0];
    const float qy = -2.0f * q[1];
    const float qz = -2.0f * q[2];

    const float sv = (lane < SPL) ? sm[lane][lq] : INFINITY;
    float mt = sv;
    #pragma unroll
    for (int off = 32; off > 0; off >>= 1) mt = fminf(mt, __shfl_xor(mt, off));
    unsigned long long flags = __ballot(sv <= mt + TAU);

    float bd = INFINITY;
    int bi = 0x7fffffff;
    while (flags) {
      const int s = __ffsll((long long)flags) - 1;   // ascending split order
      flags &= flags - 1;
      for (int it = 0; it < NIT; ++it) {
        const int m = s * SLICE + it * 64 + lane;    // per-lane increasing m
        const float* c = cbb + (size_t)m * 3;
        const float bx = c[0], by = c[1], bz = c[2];
        const float b2 = fmaf(bx, bx, fmaf(by, by, bz * bz));
        const float dd = fmaf(qx, bx, fmaf(qy, by, fmaf(qz, bz, b2)));
        if (dd < bd) { bd = dd; bi = m; }            // strict <: first-min
      }
    }
    #pragma unroll
    for (int off = 32; off > 0; off >>= 1) {
      const float od = __shfl_xor(bd, off);
      const int oi = __shfl_xor(bi, off);
      if (od < bd || (od == bd && oi < bi)) { bd = od; bi = oi; }
    }
    if (lane == 0) idx_all[qid0 + lq] = bi;
  }
}

// ---------------------------------------------------------------------------
// Pass 3 (R9-proven): loss + fused finalize via return-value-ordered atomics.
// loss = 0.25 * (sum of 4 squared-norm sums) / (B*N)
// ---------------------------------------------------------------------------
__device__ __forceinline__ float3 ld3(const float* __restrict__ p, int i) {
  const float* q = p + (size_t)i * 3;
  return make_float3(q[0], q[1], q[2]);
}

__device__ __forceinline__ float diff_nrm2(float3 a1, float3 a2, float3 b1, float3 b2) {
  const float x = (a1.x - a2.x) - (b1.x - b2.x);
  const float y = (a1.y - a2.y) - (b1.y - b2.y);
  const float z = (a1.z - a2.z) - (b1.z - b2.z);
  return fmaf(x, x, fmaf(y, y, z * z));
}

__global__ __launch_bounds__(256) void loss_final_kernel(
    const float* __restrict__ pw, const float* __restrict__ pp,
    const float* __restrict__ tw, const float* __restrict__ tp,
    const int* __restrict__ ipw, const int* __restrict__ itw,
    const int* __restrict__ ipp, const int* __restrict__ itp,
    const int* __restrict__ idx_all, double* __restrict__ acc,
    unsigned int* __restrict__ ticket, float* __restrict__ out) {
  __shared__ double sd[4];

  const int gid = blockIdx.x * 256 + threadIdx.x;  // [0, B*N)
  const int term = blockIdx.y;
  const int b = gid >> 13;
  const int n = gid & (NPTS - 1);
  const int base = b * NPTS;

  const float* PW = pw + (size_t)base * 3;
  const float* PP = pp + (size_t)base * 3;
  const float* TW = tw + (size_t)base * 3;
  const float* TP = tp + (size_t)base * 3;
  const int* I1P = idx_all + (0 * BATCH + b) * NPTS;
  const int* I2P = idx_all + (1 * BATCH + b) * NPTS;
  const int* I1T = idx_all + (2 * BATCH + b) * NPTS;
  const int* I2T = idx_all + (3 * BATCH + b) * NPTS;

  float sv;
  if (term == 0) {
    const int j = ipw[base + n];
    sv = diff_nrm2(ld3(PP, I1P[n]), ld3(PW, n), ld3(TP, I1T[j]), ld3(TW, j));
  } else if (term == 1) {
    const int k = itw[base + n];
    sv = diff_nrm2(ld3(PP, I1P[k]), ld3(PW, k), ld3(TP, I1T[n]), ld3(TW, n));
  } else if (term == 2) {
    const int j = ipp[base + n];
    sv = diff_nrm2(ld3(PP, n), ld3(PW, I2P[n]), ld3(TP, j), ld3(TW, I2T[j]));
  } else {
    const int k = itp[base + n];
    sv = diff_nrm2(ld3(PP, k), ld3(PW, I2P[k]), ld3(TP, n), ld3(TW, I2T[n]));
  }

  double ds = (double)sv;
  #pragma unroll
  for (int o = 32; o > 0; o >>= 1) ds += __shfl_down(ds, o, 64);
  if ((threadIdx.x & 63) == 0) sd[threadIdx.x >> 6] = ds;
  __syncthreads();

  if (threadIdx.x == 0) {
    const double bsum = sd[0] + sd[1] + sd[2] + sd[3];
    const double old = atomicAdd(acc, bsum);       // return forces completion
    const unsigned int inc = 1u + (unsigned int)(((unsigned long long)
                             __double_as_longlong(old)) & 0ull);
    const unsigned int total = gridDim.x * gridDim.y;   // 512
    const unsigned int t = atomicAdd(ticket, inc);
    if (t == total - 1u) {
      const double fin = atomicAdd(acc, 0.0);
      out[0] = (float)(0.25 * fin / (double)BN);
    }
  }
}

// ---------------------------------------------------------------------------
template <int SPL>
static void run_pipeline(const float* pw, const float* pp, const float* tw,
                         const float* tp, const int* ipw, const int* itw,
                         const int* ipp, const int* itp, char* ws, float* out,
                         hipStream_t stream) {
  double* acc = (double*)ws;
  unsigned int* ticket = (unsigned int*)(ws + 8);
  int* idx_all = (int*)(ws + 64);
  float* part_d = (float*)(ws + 64 + (size_t)QN * 4);
  unsigned short* bpack =
      (unsigned short*)(ws + 64 + (size_t)QN * 4 + (size_t)SPL * QN * 4);

  pack_kernel<<<QN / 256, 256, 0, stream>>>(pw, pp, tw, tp, bpack);

  dim3 grid_scan(NPTS / 256, SPL, NZB);
  nn_mfma_scan<SPL><<<grid_scan, 256, 0, stream>>>(pw, pp, tw, tp, bpack,
                                                   part_d);
  nn_merge_flag_rescan<SPL><<<QN / 64, 1024, 0, stream>>>(
      pw, pp, tw, tp, part_d, idx_all, acc, ticket);

  dim3 grid_loss(BN / 256, 4);
  loss_final_kernel<<<grid_loss, 256, 0, stream>>>(
      pw, pp, tw, tp, ipw, itw, ipp, itp, idx_all, acc, ticket, out);
}

extern "C" void kernel_launch(void* const* d_in, const int* in_sizes, int n_in,
                              void* d_out, int out_size, void* d_ws, size_t ws_size,
                              hipStream_t stream) {
  const float* pw = (const float*)d_in[0];
  const float* pp = (const float*)d_in[1];
  const float* tw = (const float*)d_in[2];
  const float* tp = (const float*)d_in[3];
  const int* ipw = (const int*)d_in[4];
  const int* itw = (const int*)d_in[5];
  const int* ipp = (const int*)d_in[6];
  const int* itp = (const int*)d_in[7];
  char* ws = (char*)d_ws;
  float* out = (float*)d_out;

  // need(SPL) = 64 + idx(512K) + part_d(SPL*512K) + bpack(4MB)
  const size_t base_need = 64 + (size_t)QN * 4 + (size_t)QN * 32;
  const size_t per_spl = (size_t)QN * 4;
  if (ws_size >= base_need + 16 * per_spl) {
    run_pipeline<16>(pw, pp, tw, tp, ipw, itw, ipp, itp, ws, out, stream);
  } else {
    run_pipeline<8>(pw, pp, tw, tp, ipw, itw, ipp, itp, ws, out, stream);
  }
}

// Round 12
// 181.334 us; speedup vs baseline: 1.3745x; 1.3745x over previous
//
#include <hip/hip_runtime.h>
#include <math.h>

// Problem constants (reference: B=4, N=8192, points are [B,N,3] fp32)
#define BATCH 4
#define NPTS 8192
#define BN (BATCH * NPTS)
#define NZB 16                 // 4 searches x 4 batches
#define QK 8                   // queries per lane in the scan
#define QBLK (256 * QK)        // 2048 queries per scan block
#define SUBT 64                // provenance subtile (rescan covers this many)

// Workspace: [0] double acc | [8] uint ticket | [64] int idx_all[NZB*NPTS]
//            [64+512K] float part_d[SPL][NZB*NPTS]
//            [after]   u8    part_t[SPL][NZB*NPTS]  (global subtile id, <128)

__device__ __forceinline__ void pick_ab(int z, const float* pw, const float* pp,
                                        const float* tw, const float* tp,
                                        const float** qa, const float** cb) {
  if (z == 0)      { *qa = pw; *cb = pp; }
  else if (z == 1) { *qa = pp; *cb = pw; }
  else if (z == 2) { *qa = tw; *cb = tp; }
  else             { *qa = tp; *cb = tw; }
}

// ---------------------------------------------------------------------------
// Pass 1 (proven, ~83us): min-distance scan + subtile provenance.
// ~3.6 cyc/wave-instr vs measured practical fp32 issue ~3.05 — near ceiling.
// MFMA reformulations measured SLOWER (R10: 98.5us, R11: 94.6us) — the
// min-reduction costs >=1 VALU op/element regardless, and K=3 MFMA
// prologue/epilogue never amortizes. This fp32 form is the empirical best.
// ---------------------------------------------------------------------------
template <int SPL>
__global__ __launch_bounds__(256, 4) void nn_partial_kernel(
    const float* __restrict__ pw, const float* __restrict__ pp,
    const float* __restrict__ tw, const float* __restrict__ tp,
    float* __restrict__ part_d, unsigned char* __restrict__ part_t) {
  constexpr int SLICE = NPTS / SPL;
  constexpr int NSUB = SLICE / SUBT;
  __shared__ float4 sh[SLICE];

  const int zb = blockIdx.z;
  const int z = zb >> 2;
  const int b = zb & 3;
  const float* qa;
  const float* cb;
  pick_ab(z, pw, pp, tw, tp, &qa, &cb);

  const int tid = threadIdx.x;
  const int cslice = blockIdx.y * SLICE;
  const float* cbb = cb + (size_t)b * NPTS * 3;

  // Stage slice as (x,y,z,||b||^2); formulas must match rescan exactly.
  for (int m = tid; m < SLICE; m += 256) {
    const float* c = cbb + (size_t)(cslice + m) * 3;
    const float bx = c[0], by = c[1], bz = c[2];
    sh[m] = make_float4(bx, by, bz, fmaf(bx, bx, fmaf(by, by, bz * bz)));
  }
  __syncthreads();

  const int qbase = blockIdx.x * QBLK;
  float qx[QK], qy[QK], qz[QK], dmin[QK];
  int tile[QK];
  #pragma unroll
  for (int k = 0; k < QK; ++k) {
    const int n = qbase + tid + k * 256;
    const float* q = qa + ((size_t)b * NPTS + n) * 3;
    qx[k] = -2.0f * q[0];
    qy[k] = -2.0f * q[1];
    qz[k] = -2.0f * q[2];
    dmin[k] = INFINITY;
    tile[k] = 0;
  }

  for (int sub = 0; sub < NSUB; ++sub) {
    float pre[QK];
    #pragma unroll
    for (int k = 0; k < QK; ++k) pre[k] = dmin[k];

    const int cb0 = sub * SUBT;
    #pragma unroll 2
    for (int p = 0; p < SUBT / 2; ++p) {
      const float4 c0 = sh[cb0 + 2 * p];
      const float4 c1 = sh[cb0 + 2 * p + 1];
      float t0[QK], t1[QK];
      #pragma unroll
      for (int k = 0; k < QK; ++k)
        t0[k] = fmaf(qx[k], c0.x, fmaf(qy[k], c0.y, fmaf(qz[k], c0.z, c0.w)));
      #pragma unroll
      for (int k = 0; k < QK; ++k)
        t1[k] = fmaf(qx[k], c1.x, fmaf(qy[k], c1.y, fmaf(qz[k], c1.z, c1.w)));
      #pragma unroll
      for (int k = 0; k < QK; ++k)
        dmin[k] = fminf(fminf(t0[k], t1[k]), dmin[k]);   // v_min3_f32
    }
    const int g = blockIdx.y * NSUB + sub;   // global subtile id, [0,128)
    #pragma unroll
    for (int k = 0; k < QK; ++k)
      tile[k] = (dmin[k] < pre[k]) ? g : tile[k];  // strict <: first-min kept
  }

  #pragma unroll
  for (int k = 0; k < QK; ++k) {
    const int n = qbase + tid + k * 256;
    const size_t o = (size_t)blockIdx.y * (NZB * NPTS) + (size_t)zb * NPTS + n;
    part_d[o] = dmin[k];
    part_t[o] = (unsigned char)tile[k];
  }
}

// ---------------------------------------------------------------------------
// Pass 2 (proven R8 shape): fused merge + rescan. Block = 1024 (16 waves)
// covers 64 consecutive queries. Also zeroes acc + ticket for pass 3.
// ---------------------------------------------------------------------------
template <int SPL>
__global__ __launch_bounds__(1024) void nn_merge_rescan_kernel(
    const float* __restrict__ pw, const float* __restrict__ pp,
    const float* __restrict__ tw, const float* __restrict__ tp,
    const float* __restrict__ part_d, const unsigned char* __restrict__ part_t,
    int* __restrict__ idx_all, double* __restrict__ acc,
    unsigned int* __restrict__ ticket) {
  __shared__ float md[16][64];
  __shared__ int mg[16][64];
  __shared__ float sdq[64];
  __shared__ int sgq[64];

  if (blockIdx.x == 0 && threadIdx.x == 0) { *acc = 0.0; *ticket = 0u; }

  const int tid = threadIdx.x;
  const int wv = tid >> 6;          // wave id, 0..15
  const int lane = tid & 63;
  const int qid0 = blockIdx.x * 64;

  // --- Merge phase: coalesced plane loads, per-wave partial lexmin ---
  {
    float bd = INFINITY;
    int bg = 0x7fffffff;
    for (int s = wv; s < SPL; s += 16) {
      const size_t o = (size_t)s * (NZB * NPTS) + qid0 + lane;  // 64 consecutive
      const float d = part_d[o];
      const int g = part_t[o];
      if (d < bd || (d == bd && g < bg)) { bd = d; bg = g; }
    }
    md[wv][lane] = bd;
    mg[wv][lane] = bg;
  }
  __syncthreads();
  if (wv == 0) {                    // wave 0: final 16-way reduce per query
    float bd = md[0][lane];
    int bg = mg[0][lane];
    #pragma unroll
    for (int v = 1; v < 16; ++v) {
      const float d = md[v][lane];
      const int g = mg[v][lane];
      if (d < bd || (d == bd && g < bg)) { bd = d; bg = g; }
    }
    sdq[lane] = bd;
    sgq[lane] = bg;
  }
  __syncthreads();

  // --- Rescan phase: wave v -> queries v*4 .. v*4+3 ---
  const int zb = qid0 >> 13;        // uniform per block
  const int z = zb >> 2;
  const int b = zb & 3;
  const float* qa;
  const float* cb;
  pick_ab(z, pw, pp, tw, tp, &qa, &cb);
  const float* qb0 = qa + (size_t)b * NPTS * 3;
  const float* cbb = cb + (size_t)b * NPTS * 3;
  const int n0 = qid0 & (NPTS - 1);

  #pragma unroll
  for (int j = 0; j < 4; ++j) {
    const int lq = wv * 4 + j;
    const float best_d = sdq[lq];   // LDS broadcast
    const int best_g = sgq[lq];
    const float* q = qb0 + (size_t)(n0 + lq) * 3;   // wave-uniform 12B
    const float qx = -2.0f * q[0];
    const float qy = -2.0f * q[1];
    const float qz = -2.0f * q[2];
    const int m = best_g * SUBT + lane;             // contiguous across wave
    const float* c = cbb + (size_t)m * 3;
    const float bx = c[0], by = c[1], bz = c[2];
    const float b2 = fmaf(bx, bx, fmaf(by, by, bz * bz));
    const float dd = fmaf(qx, bx, fmaf(qy, by, fmaf(qz, bz, b2)));
    const unsigned long long hit = __ballot(dd == best_d);
    if (lane == 0)
      idx_all[qid0 + lq] = best_g * SUBT + (__ffsll((long long)hit) - 1);
  }
}

// ---------------------------------------------------------------------------
// Pass 3 (proven R9): loss (4 MSN terms split across blockIdx.y) + fused
// finalize. One acc-atomic per block; ordering via the atomic's RETURN VALUE
// before the ticket bump. Last of the 512 blocks writes out.
// loss = 0.25 * (sum of 4 squared-norm sums) / (B*N)
// ---------------------------------------------------------------------------
__device__ __forceinline__ float3 ld3(const float* __restrict__ p, int i) {
  const float* q = p + (size_t)i * 3;
  return make_float3(q[0], q[1], q[2]);
}

__device__ __forceinline__ float diff_nrm2(float3 a1, float3 a2, float3 b1, float3 b2) {
  const float x = (a1.x - a2.x) - (b1.x - b2.x);
  const float y = (a1.y - a2.y) - (b1.y - b2.y);
  const float z = (a1.z - a2.z) - (b1.z - b2.z);
  return fmaf(x, x, fmaf(y, y, z * z));
}

__global__ __launch_bounds__(256) void loss_final_kernel(
    const float* __restrict__ pw, const float* __restrict__ pp,
    const float* __restrict__ tw, const float* __restrict__ tp,
    const int* __restrict__ ipw, const int* __restrict__ itw,
    const int* __restrict__ ipp, const int* __restrict__ itp,
    const int* __restrict__ idx_all, double* __restrict__ acc,
    unsigned int* __restrict__ ticket, float* __restrict__ out) {
  __shared__ double sd[4];

  const int gid = blockIdx.x * 256 + threadIdx.x;  // [0, B*N)
  const int term = blockIdx.y;
  const int b = gid >> 13;
  const int n = gid & (NPTS - 1);
  const int base = b * NPTS;

  const float* PW = pw + (size_t)base * 3;
  const float* PP = pp + (size_t)base * 3;
  const float* TW = tw + (size_t)base * 3;
  const float* TP = tp + (size_t)base * 3;
  const int* I1P = idx_all + (0 * BATCH + b) * NPTS;  // NN pial for white (pred)
  const int* I2P = idx_all + (1 * BATCH + b) * NPTS;  // NN white for pial (pred)
  const int* I1T = idx_all + (2 * BATCH + b) * NPTS;  // NN pial for white (true)
  const int* I2T = idx_all + (3 * BATCH + b) * NPTS;  // NN white for pial (true)

  float sv;
  if (term == 0) {        // msn(yp_inner, yt_inner[i_pred_white])
    const int j = ipw[base + n];
    sv = diff_nrm2(ld3(PP, I1P[n]), ld3(PW, n), ld3(TP, I1T[j]), ld3(TW, j));
  } else if (term == 1) { // msn(yp_inner[i_true_white], yt_inner)
    const int k = itw[base + n];
    sv = diff_nrm2(ld3(PP, I1P[k]), ld3(PW, k), ld3(TP, I1T[n]), ld3(TW, n));
  } else if (term == 2) { // msn(yp_outer, yt_outer[i_pred_pial])
    const int j = ipp[base + n];
    sv = diff_nrm2(ld3(PP, n), ld3(PW, I2P[n]), ld3(TP, j), ld3(TW, I2T[j]));
  } else {                // msn(yp_outer[i_true_pial], yt_outer)
    const int k = itp[base + n];
    sv = diff_nrm2(ld3(PP, k), ld3(PW, I2P[k]), ld3(TP, n), ld3(TW, I2T[n]));
  }

  // Wave shuffle-reduce -> LDS -> single block sum.
  double ds = (double)sv;
  #pragma unroll
  for (int o = 32; o > 0; o >>= 1) ds += __shfl_down(ds, o, 64);
  if ((threadIdx.x & 63) == 0) sd[threadIdx.x >> 6] = ds;
  __syncthreads();

  if (threadIdx.x == 0) {
    const double bsum = sd[0] + sd[1] + sd[2] + sd[3];
    const double old = atomicAdd(acc, bsum);   // return forces completion
    // Data-dependency on 'old' orders the ticket bump after the acc add.
    const unsigned int inc = 1u + (unsigned int)(((unsigned long long)
                             __double_as_longlong(old)) & 0ull);
    const unsigned int total = gridDim.x * gridDim.y;   // 512
    const unsigned int t = atomicAdd(ticket, inc);
    if (t == total - 1u) {
      const double fin = atomicAdd(acc, 0.0);  // atomic read of the full sum
      out[0] = (float)(0.25 * fin / (double)BN);
    }
  }
}

// ---------------------------------------------------------------------------
template <int SPL>
static void run_pipeline(const float* pw, const float* pp, const float* tw,
                         const float* tp, const int* ipw, const int* itw,
                         const int* ipp, const int* itp, char* ws, float* out,
                         hipStream_t stream) {
  double* acc = (double*)ws;
  unsigned int* ticket = (unsigned int*)(ws + 8);
  int* idx_all = (int*)(ws + 64);
  float* part_d = (float*)(ws + 64 + (size_t)NZB * NPTS * 4);
  unsigned char* part_t =
      (unsigned char*)(ws + 64 + (size_t)NZB * NPTS * 4 +
                       (size_t)SPL * NZB * NPTS * 4);

  dim3 grid_nn(NPTS / QBLK, SPL, NZB);
  nn_partial_kernel<SPL><<<grid_nn, 256, 0, stream>>>(pw, pp, tw, tp, part_d,
                                                      part_t);
  nn_merge_rescan_kernel<SPL><<<(NZB * NPTS) / 64, 1024, 0, stream>>>(
      pw, pp, tw, tp, part_d, part_t, idx_all, acc, ticket);

  dim3 grid_loss(BN / 256, 4);
  loss_final_kernel<<<grid_loss, 256, 0, stream>>>(
      pw, pp, tw, tp, ipw, itw, ipp, itp, idx_all, acc, ticket, out);
}

extern "C" void kernel_launch(void* const* d_in, const int* in_sizes, int n_in,
                              void* d_out, int out_size, void* d_ws, size_t ws_size,
                              hipStream_t stream) {
  const float* pw = (const float*)d_in[0];
  const float* pp = (const float*)d_in[1];
  const float* tw = (const float*)d_in[2];
  const float* tp = (const float*)d_in[3];
  const int* ipw = (const int*)d_in[4];
  const int* itw = (const int*)d_in[5];
  const int* ipp = (const int*)d_in[6];
  const int* itp = (const int*)d_in[7];
  char* ws = (char*)d_ws;
  float* out = (float*)d_out;

  // ws need per SPL: 64 + idx(512K) + part_d(SPL*512K) + part_t(SPL*128K)
  const size_t base_need = 64 + (size_t)NZB * NPTS * 4;
  const size_t per_spl = (size_t)NZB * NPTS * 5;
  if (ws_size >= base_need + 32 * per_spl) {
    run_pipeline<32>(pw, pp, tw, tp, ipw, itw, ipp, itp, ws, out, stream);
  } else if (ws_size >= base_need + 16 * per_spl) {
    run_pipeline<16>(pw, pp, tw, tp, ipw, itw, ipp, itp, ws, out, stream);
  } else {
    run_pipeline<8>(pw, pp, tw, tp, ipw, itw, ipp, itp, ws, out, stream);
  }
}

// Round 13
// 181.266 us; speedup vs baseline: 1.3751x; 1.0004x over previous
//
#include <hip/hip_runtime.h>
#include <math.h>

// Problem constants (reference: B=4, N=8192, points are [B,N,3] fp32)
#define BATCH 4
#define NPTS 8192
#define BN (BATCH * NPTS)
#define NZB 16                 // 4 searches x 4 batches
#define QK 8                   // queries per lane in the scan
#define QBLK (256 * QK)        // 2048 queries per scan block
#define SUBT 64                // provenance subtile (rescan covers this many)

// Workspace: [0] double acc | [8] uint ticket | [64] int idx_all[NZB*NPTS]
//            [64+512K] float part_d[SPL][NZB*NPTS]
//            [after]   u8    part_t[SPL][NZB*NPTS]  (global subtile id, <128)

typedef float v2f __attribute__((ext_vector_type(2)));

// Two independent fp32 FMAs in one VOP3P instruction. Each half is
// bit-identical to v_fma_f32 (same IEEE rounding) — preserves the
// scan<->rescan exact-match invariant.
__device__ __forceinline__ v2f pk_fma(v2f a, v2f b, v2f c) {
  v2f d;
  asm("v_pk_fma_f32 %0, %1, %2, %3" : "=v"(d) : "v"(a), "v"(b), "v"(c));
  return d;
}

__device__ __forceinline__ void pick_ab(int z, const float* pw, const float* pp,
                                        const float* tw, const float* tp,
                                        const float** qa, const float** cb) {
  if (z == 0)      { *qa = pw; *cb = pp; }
  else if (z == 1) { *qa = pp; *cb = pw; }
  else if (z == 2) { *qa = tw; *cb = tp; }
  else             { *qa = tp; *cb = tw; }
}

// ---------------------------------------------------------------------------
// Pass 1: packed-fp32 min-distance scan + subtile provenance.
// Candidates processed in pairs packed into float2 lanes:
//   t = pk_fma(qx, x01, pk_fma(qy, y01, pk_fma(qz, z01, b2_01)))
//   dmin = min3(t.lo, t.hi, dmin)
// = 2.0 VALU instr per (query, candidate) pair vs 3.5 scalar (R12: 85us).
// LDS: pair-interleaved [x01 y01 z01 b2_01] 32B/pair, wave-broadcast reads.
// ---------------------------------------------------------------------------
template <int SPL>
__global__ __launch_bounds__(256, 4) void nn_partial_kernel(
    const float* __restrict__ pw, const float* __restrict__ pp,
    const float* __restrict__ tw, const float* __restrict__ tp,
    float* __restrict__ part_d, unsigned char* __restrict__ part_t) {
  constexpr int SLICE = NPTS / SPL;
  constexpr int NSUB = SLICE / SUBT;
  __shared__ __align__(16) v2f sh2[(SLICE / 2) * 4];   // 32B per candidate pair

  const int zb = blockIdx.z;
  const int z = zb >> 2;
  const int b = zb & 3;
  const float* qa;
  const float* cb;
  pick_ab(z, pw, pp, tw, tp, &qa, &cb);

  const int tid = threadIdx.x;
  const int cslice = blockIdx.y * SLICE;
  const float* cbb = cb + (size_t)b * NPTS * 3;

  // Stage candidate pairs; b2 formula must match the rescan exactly.
  for (int p = tid; p < SLICE / 2; p += 256) {
    const float* c = cbb + (size_t)(cslice + 2 * p) * 3;
    const float b0x = c[0], b0y = c[1], b0z = c[2];
    const float b1x = c[3], b1y = c[4], b1z = c[5];
    const float b20 = fmaf(b0x, b0x, fmaf(b0y, b0y, b0z * b0z));
    const float b21 = fmaf(b1x, b1x, fmaf(b1y, b1y, b1z * b1z));
    sh2[p * 4 + 0] = (v2f){b0x, b1x};
    sh2[p * 4 + 1] = (v2f){b0y, b1y};
    sh2[p * 4 + 2] = (v2f){b0z, b1z};
    sh2[p * 4 + 3] = (v2f){b20, b21};
  }
  __syncthreads();

  const int qbase = blockIdx.x * QBLK;
  v2f qx2[QK], qy2[QK], qz2[QK];
  float dmin[QK];
  int tile[QK];
  #pragma unroll
  for (int k = 0; k < QK; ++k) {
    const int n = qbase + tid + k * 256;
    const float* q = qa + ((size_t)b * NPTS + n) * 3;
    const float qx = -2.0f * q[0];
    const float qy = -2.0f * q[1];
    const float qz = -2.0f * q[2];
    qx2[k] = (v2f){qx, qx};
    qy2[k] = (v2f){qy, qy};
    qz2[k] = (v2f){qz, qz};
    dmin[k] = INFINITY;
    tile[k] = 0;
  }

  for (int sub = 0; sub < NSUB; ++sub) {
    float pre[QK];
    #pragma unroll
    for (int k = 0; k < QK; ++k) pre[k] = dmin[k];

    const int pb = sub * (SUBT / 2);
    #pragma unroll 2
    for (int p = 0; p < SUBT / 2; ++p) {
      const v2f cx = sh2[(pb + p) * 4 + 0];
      const v2f cy = sh2[(pb + p) * 4 + 1];
      const v2f cz = sh2[(pb + p) * 4 + 2];
      const v2f cw = sh2[(pb + p) * 4 + 3];
      #pragma unroll
      for (int k = 0; k < QK; ++k) {
        const v2f t =
            pk_fma(qx2[k], cx, pk_fma(qy2[k], cy, pk_fma(qz2[k], cz, cw)));
        dmin[k] = fminf(fminf(t.x, t.y), dmin[k]);   // v_min3_f32
      }
    }
    const int g = blockIdx.y * NSUB + sub;   // global subtile id, [0,128)
    #pragma unroll
    for (int k = 0; k < QK; ++k)
      tile[k] = (dmin[k] < pre[k]) ? g : tile[k];  // strict <: first-min kept
  }

  #pragma unroll
  for (int k = 0; k < QK; ++k) {
    const int n = qbase + tid + k * 256;
    const size_t o = (size_t)blockIdx.y * (NZB * NPTS) + (size_t)zb * NPTS + n;
    part_d[o] = dmin[k];
    part_t[o] = (unsigned char)tile[k];
  }
}

// ---------------------------------------------------------------------------
// Pass 2 (proven R8 shape): fused merge + rescan. Block = 1024 (16 waves)
// covers 64 consecutive queries. Also zeroes acc + ticket for pass 3.
// ---------------------------------------------------------------------------
template <int SPL>
__global__ __launch_bounds__(1024) void nn_merge_rescan_kernel(
    const float* __restrict__ pw, const float* __restrict__ pp,
    const float* __restrict__ tw, const float* __restrict__ tp,
    const float* __restrict__ part_d, const unsigned char* __restrict__ part_t,
    int* __restrict__ idx_all, double* __restrict__ acc,
    unsigned int* __restrict__ ticket) {
  __shared__ float md[16][64];
  __shared__ int mg[16][64];
  __shared__ float sdq[64];
  __shared__ int sgq[64];

  if (blockIdx.x == 0 && threadIdx.x == 0) { *acc = 0.0; *ticket = 0u; }

  const int tid = threadIdx.x;
  const int wv = tid >> 6;          // wave id, 0..15
  const int lane = tid & 63;
  const int qid0 = blockIdx.x * 64;

  // --- Merge phase: coalesced plane loads, per-wave partial lexmin ---
  {
    float bd = INFINITY;
    int bg = 0x7fffffff;
    for (int s = wv; s < SPL; s += 16) {
      const size_t o = (size_t)s * (NZB * NPTS) + qid0 + lane;  // 64 consecutive
      const float d = part_d[o];
      const int g = part_t[o];
      if (d < bd || (d == bd && g < bg)) { bd = d; bg = g; }
    }
    md[wv][lane] = bd;
    mg[wv][lane] = bg;
  }
  __syncthreads();
  if (wv == 0) {                    // wave 0: final 16-way reduce per query
    float bd = md[0][lane];
    int bg = mg[0][lane];
    #pragma unroll
    for (int v = 1; v < 16; ++v) {
      const float d = md[v][lane];
      const int g = mg[v][lane];
      if (d < bd || (d == bd && g < bg)) { bd = d; bg = g; }
    }
    sdq[lane] = bd;
    sgq[lane] = bg;
  }
  __syncthreads();

  // --- Rescan phase: wave v -> queries v*4 .. v*4+3 ---
  const int zb = qid0 >> 13;        // uniform per block
  const int z = zb >> 2;
  const int b = zb & 3;
  const float* qa;
  const float* cb;
  pick_ab(z, pw, pp, tw, tp, &qa, &cb);
  const float* qb0 = qa + (size_t)b * NPTS * 3;
  const float* cbb = cb + (size_t)b * NPTS * 3;
  const int n0 = qid0 & (NPTS - 1);

  #pragma unroll
  for (int j = 0; j < 4; ++j) {
    const int lq = wv * 4 + j;
    const float best_d = sdq[lq];   // LDS broadcast
    const int best_g = sgq[lq];
    const float* q = qb0 + (size_t)(n0 + lq) * 3;   // wave-uniform 12B
    const float qx = -2.0f * q[0];
    const float qy = -2.0f * q[1];
    const float qz = -2.0f * q[2];
    const int m = best_g * SUBT + lane;             // contiguous across wave
    const float* c = cbb + (size_t)m * 3;
    const float bx = c[0], by = c[1], bz = c[2];
    const float b2 = fmaf(bx, bx, fmaf(by, by, bz * bz));
    const float dd = fmaf(qx, bx, fmaf(qy, by, fmaf(qz, bz, b2)));
    const unsigned long long hit = __ballot(dd == best_d);
    if (lane == 0)
      idx_all[qid0 + lq] = best_g * SUBT + (__ffsll((long long)hit) - 1);
  }
}

// ---------------------------------------------------------------------------
// Pass 3 (proven R9): loss (4 MSN terms split across blockIdx.y) + fused
// finalize. One acc-atomic per block; ordering via the atomic's RETURN VALUE
// before the ticket bump. Last of the 512 blocks writes out.
// loss = 0.25 * (sum of 4 squared-norm sums) / (B*N)
// ---------------------------------------------------------------------------
__device__ __forceinline__ float3 ld3(const float* __restrict__ p, int i) {
  const float* q = p + (size_t)i * 3;
  return make_float3(q[0], q[1], q[2]);
}

__device__ __forceinline__ float diff_nrm2(float3 a1, float3 a2, float3 b1, float3 b2) {
  const float x = (a1.x - a2.x) - (b1.x - b2.x);
  const float y = (a1.y - a2.y) - (b1.y - b2.y);
  const float z = (a1.z - a2.z) - (b1.z - b2.z);
  return fmaf(x, x, fmaf(y, y, z * z));
}

__global__ __launch_bounds__(256) void loss_final_kernel(
    const float* __restrict__ pw, const float* __restrict__ pp,
    const float* __restrict__ tw, const float* __restrict__ tp,
    const int* __restrict__ ipw, const int* __restrict__ itw,
    const int* __restrict__ ipp, const int* __restrict__ itp,
    const int* __restrict__ idx_all, double* __restrict__ acc,
    unsigned int* __restrict__ ticket, float* __restrict__ out) {
  __shared__ double sd[4];

  const int gid = blockIdx.x * 256 + threadIdx.x;  // [0, B*N)
  const int term = blockIdx.y;
  const int b = gid >> 13;
  const int n = gid & (NPTS - 1);
  const int base = b * NPTS;

  const float* PW = pw + (size_t)base * 3;
  const float* PP = pp + (size_t)base * 3;
  const float* TW = tw + (size_t)base * 3;
  const float* TP = tp + (size_t)base * 3;
  const int* I1P = idx_all + (0 * BATCH + b) * NPTS;  // NN pial for white (pred)
  const int* I2P = idx_all + (1 * BATCH + b) * NPTS;  // NN white for pial (pred)
  const int* I1T = idx_all + (2 * BATCH + b) * NPTS;  // NN pial for white (true)
  const int* I2T = idx_all + (3 * BATCH + b) * NPTS;  // NN white for pial (true)

  float sv;
  if (term == 0) {        // msn(yp_inner, yt_inner[i_pred_white])
    const int j = ipw[base + n];
    sv = diff_nrm2(ld3(PP, I1P[n]), ld3(PW, n), ld3(TP, I1T[j]), ld3(TW, j));
  } else if (term == 1) { // msn(yp_inner[i_true_white], yt_inner)
    const int k = itw[base + n];
    sv = diff_nrm2(ld3(PP, I1P[k]), ld3(PW, k), ld3(TP, I1T[n]), ld3(TW, n));
  } else if (term == 2) { // msn(yp_outer, yt_outer[i_pred_pial])
    const int j = ipp[base + n];
    sv = diff_nrm2(ld3(PP, n), ld3(PW, I2P[n]), ld3(TP, j), ld3(TW, I2T[j]));
  } else {                // msn(yp_outer[i_true_pial], yt_outer)
    const int k = itp[base + n];
    sv = diff_nrm2(ld3(PP, k), ld3(PW, I2P[k]), ld3(TP, n), ld3(TW, I2T[n]));
  }

  // Wave shuffle-reduce -> LDS -> single block sum.
  double ds = (double)sv;
  #pragma unroll
  for (int o = 32; o > 0; o >>= 1) ds += __shfl_down(ds, o, 64);
  if ((threadIdx.x & 63) == 0) sd[threadIdx.x >> 6] = ds;
  __syncthreads();

  if (threadIdx.x == 0) {
    const double bsum = sd[0] + sd[1] + sd[2] + sd[3];
    const double old = atomicAdd(acc, bsum);   // return forces completion
    // Data-dependency on 'old' orders the ticket bump after the acc add.
    const unsigned int inc = 1u + (unsigned int)(((unsigned long long)
                             __double_as_longlong(old)) & 0ull);
    const unsigned int total = gridDim.x * gridDim.y;   // 512
    const unsigned int t = atomicAdd(ticket, inc);
    if (t == total - 1u) {
      const double fin = atomicAdd(acc, 0.0);  // atomic read of the full sum
      out[0] = (float)(0.25 * fin / (double)BN);
    }
  }
}

// ---------------------------------------------------------------------------
template <int SPL>
static void run_pipeline(const float* pw, const float* pp, const float* tw,
                         const float* tp, const int* ipw, const int* itw,
                         const int* ipp, const int* itp, char* ws, float* out,
                         hipStream_t stream) {
  double* acc = (double*)ws;
  unsigned int* ticket = (unsigned int*)(ws + 8);
  int* idx_all = (int*)(ws + 64);
  float* part_d = (float*)(ws + 64 + (size_t)NZB * NPTS * 4);
  unsigned char* part_t =
      (unsigned char*)(ws + 64 + (size_t)NZB * NPTS * 4 +
                       (size_t)SPL * NZB * NPTS * 4);

  dim3 grid_nn(NPTS / QBLK, SPL, NZB);
  nn_partial_kernel<SPL><<<grid_nn, 256, 0, stream>>>(pw, pp, tw, tp, part_d,
                                                      part_t);
  nn_merge_rescan_kernel<SPL><<<(NZB * NPTS) / 64, 1024, 0, stream>>>(
      pw, pp, tw, tp, part_d, part_t, idx_all, acc, ticket);

  dim3 grid_loss(BN / 256, 4);
  loss_final_kernel<<<grid_loss, 256, 0, stream>>>(
      pw, pp, tw, tp, ipw, itw, ipp, itp, idx_all, acc, ticket, out);
}

extern "C" void kernel_launch(void* const* d_in, const int* in_sizes, int n_in,
                              void* d_out, int out_size, void* d_ws, size_t ws_size,
                              hipStream_t stream) {
  const float* pw = (const float*)d_in[0];
  const float* pp = (const float*)d_in[1];
  const float* tw = (const float*)d_in[2];
  const float* tp = (const float*)d_in[3];
  const int* ipw = (const int*)d_in[4];
  const int* itw = (const int*)d_in[5];
  const int* ipp = (const int*)d_in[6];
  const int* itp = (const int*)d_in[7];
  char* ws = (char*)d_ws;
  float* out = (float*)d_out;

  // ws need per SPL: 64 + idx(512K) + part_d(SPL*512K) + part_t(SPL*128K)
  const size_t base_need = 64 + (size_t)NZB * NPTS * 4;
  const size_t per_spl = (size_t)NZB * NPTS * 5;
  if (ws_size >= base_need + 32 * per_spl) {
    run_pipeline<32>(pw, pp, tw, tp, ipw, itw, ipp, itp, ws, out, stream);
  } else if (ws_size >= base_need + 16 * per_spl) {
    run_pipeline<16>(pw, pp, tw, tp, ipw, itw, ipp, itp, ws, out, stream);
  } else {
    run_pipeline<8>(pw, pp, tw, tp, ipw, itw, ipp, itp, ws, out, stream);
  }
}